// Round 1
// baseline (133.967 us; speedup 1.0000x reference)
//
#include <hip/hip_runtime.h>
#include <math.h>

#define HH 512
#define WW 512
#define CC 64
#define HWHW (HH * WW)
#define NBOX 30
#define KTOP 10
#define NBLK 1024              // (H*W)/256 peak blocks per batch

// ---------------- Kernel 1: intensity = sqrt(sum_c loc^2) ----------------
__global__ void k_intensity(const float* __restrict__ loc, float* __restrict__ inten) {
    int id = blockIdx.x * blockDim.x + threadIdx.x;   // over B*HW/4
    int b  = id / (HWHW / 4);
    int p4 = id - b * (HWHW / 4);
    const float4* base = reinterpret_cast<const float4*>(loc + (size_t)b * CC * HWHW) + p4;
    float ax = 0.f, ay = 0.f, az = 0.f, aw = 0.f;
    #pragma unroll 8
    for (int c = 0; c < CC; ++c) {
        float4 v = base[(size_t)c * (HWHW / 4)];
        ax += v.x * v.x; ay += v.y * v.y; az += v.z * v.z; aw += v.w * v.w;
    }
    float4 o;
    o.x = sqrtf(ax); o.y = sqrtf(ay); o.z = sqrtf(az); o.w = sqrtf(aw);
    reinterpret_cast<float4*>(inten)[id] = o;
}

// ---------------- Kernel 2: peak detect + per-block top-10 ----------------
// grid = B*NBLK blocks of 256 threads; each block covers 256 contiguous pixels.
__global__ void k_peaks(const float* __restrict__ inten,
                        float* __restrict__ cval, int* __restrict__ cidx) {
    int t    = threadIdx.x;
    int blk  = blockIdx.x;            // b*NBLK + pblk
    int b    = blk / NBLK;
    int pblk = blk - b * NBLK;
    int pix  = pblk * 256 + t;        // flat pixel index in [0, HW)
    int y = pix >> 9;
    int x = pix & (WW - 1);
    const float* I = inten + (size_t)b * HWHW;

    float v = I[pix];
    float m = v;
    #pragma unroll
    for (int dy = -1; dy <= 1; ++dy) {
        int yy = y + dy;
        if (yy < 0 || yy >= HH) continue;
        #pragma unroll
        for (int dx = -1; dx <= 1; ++dx) {
            int xx = x + dx;
            if (xx < 0 || xx >= WW) continue;
            m = fmaxf(m, I[yy * WW + xx]);
        }
    }
    bool peak = (v > 0.5f) && (v == m);
    float val = peak ? v : -INFINITY;
    int   idx = pix;

    __shared__ float sv[256];
    __shared__ int   si[256];
    for (int r = 0; r < KTOP; ++r) {
        sv[t] = val; si[t] = idx;
        __syncthreads();
        for (int s = 128; s > 0; s >>= 1) {
            if (t < s) {
                float ov = sv[t + s]; int oi = si[t + s];
                if (ov > sv[t] || (ov == sv[t] && oi < si[t])) { sv[t] = ov; si[t] = oi; }
            }
            __syncthreads();
        }
        float wv = sv[0]; int wi = si[0];
        if (t == 0) { cval[blk * KTOP + r] = wv; cidx[blk * KTOP + r] = wi; }
        __syncthreads();
        if (wi == idx) val = -INFINITY;   // idx unique per thread -> exactly one marks
    }
}

// ---------------- Kernel 3: global top-10 + gather + cosine loss ----------------
// grid = B blocks of 256 threads.
__global__ void k_loss(const float* __restrict__ loc, const float* __restrict__ det,
                       const float* __restrict__ boxes,
                       const float* __restrict__ cval, const int* __restrict__ cidx,
                       float* __restrict__ bloss) {
    int b = blockIdx.x;
    int t = threadIdx.x;

    // --- per-thread sorted top-10 over its 40 candidates (order: val desc, idx asc) ---
    float lv[KTOP]; int li[KTOP];
    #pragma unroll
    for (int i = 0; i < KTOP; ++i) { lv[i] = -INFINITY; li[i] = 0x7fffffff; }
    const float* CV = cval + (size_t)b * (NBLK * KTOP);
    const int*   CI = cidx + (size_t)b * (NBLK * KTOP);
    for (int j = 0; j < 40; ++j) {
        float v  = CV[t * 40 + j];
        int   id = CI[t * 40 + j];
        if (v > lv[KTOP - 1] || (v == lv[KTOP - 1] && id < li[KTOP - 1])) {
            lv[KTOP - 1] = v; li[KTOP - 1] = id;
            #pragma unroll
            for (int m = KTOP - 1; m > 0; --m) {
                bool better = lv[m] > lv[m - 1] || (lv[m] == lv[m - 1] && li[m] < li[m - 1]);
                if (better) {
                    float tv = lv[m]; lv[m] = lv[m - 1]; lv[m - 1] = tv;
                    int   ti = li[m]; li[m] = li[m - 1]; li[m - 1] = ti;
                }
            }
        }
    }

    // --- 10-round k-way merge of thread heads -> global top-10 ---
    __shared__ float hv[256];
    __shared__ int   hi[256];
    __shared__ float topv[KTOP];
    __shared__ int   topi[KTOP];
    for (int r = 0; r < KTOP; ++r) {
        hv[t] = lv[0]; hi[t] = li[0];
        __syncthreads();
        for (int s = 128; s > 0; s >>= 1) {
            if (t < s) {
                float ov = hv[t + s]; int oi = hi[t + s];
                if (ov > hv[t] || (ov == hv[t] && oi < hi[t])) { hv[t] = ov; hi[t] = oi; }
            }
            __syncthreads();
        }
        float wv = hv[0]; int wi = hi[0];
        if (t == 0) { topv[r] = wv; topi[r] = wi; }
        __syncthreads();
        if (li[0] == wi && lv[0] == wv) {   // winner owner pops its head
            #pragma unroll
            for (int m = 0; m < KTOP - 1; ++m) { lv[m] = lv[m + 1]; li[m] = li[m + 1]; }
            lv[KTOP - 1] = -INFINITY; li[KTOP - 1] = 0x7fffffff;
        }
    }

    // --- box centers + static mask ---
    __shared__ int   s_cx[NBOX], s_cy[NBOX], s_static[NBOX];
    if (t < NBOX) {
        const float* bx = boxes + ((size_t)b * NBOX + t) * 8;
        float fx = (bx[0] + 59.9f) / 119.8f * 512.0f;
        float fy = (bx[1] + 59.9f) / 119.8f * 512.0f;
        int cx = (int)fx; int cy = (int)fy;            // trunc == astype(int32)
        cx = min(max(cx, 0), WW - 1);
        cy = min(max(cy, 0), HH - 1);
        s_cx[t] = cx; s_cy[t] = cy;
        s_static[t] = (bx[7] == 0.0f) ? 1 : 0;
    }
    __syncthreads();

    // --- gathers ---
    __shared__ float pf[KTOP][CC];
    __shared__ float df[NBOX][CC];
    for (int e = t; e < KTOP * CC; e += 256) {
        int k = e >> 6, c = e & 63;
        int pix = (topv[k] > -INFINITY) ? topi[k] : 0;   // guard: invalid -> masked later
        pf[k][c] = loc[((size_t)b * CC + c) * HWHW + pix];
    }
    for (int e = t; e < NBOX * CC; e += 256) {
        int n = e >> 6, c = e & 63;
        int pix = s_cy[n] * WW + s_cx[n];
        df[n][c] = det[((size_t)b * CC + c) * HWHW + pix];
    }
    __syncthreads();

    // --- torch-eps cosine normalization ---
    __shared__ float invn[NBOX + KTOP];
    if (t < NBOX + KTOP) {
        float s = 0.f;
        if (t < NBOX) {
            for (int c = 0; c < CC; ++c) s += df[t][c] * df[t][c];
        } else {
            int k = t - NBOX;
            for (int c = 0; c < CC; ++c) s += pf[k][c] * pf[k][c];
        }
        invn[t] = 1.0f / fmaxf(sqrtf(s), 1e-8f);
    }
    __syncthreads();
    for (int e = t; e < NBOX * CC; e += 256) { int n = e >> 6; df[n][e & 63] *= invn[n]; }
    for (int e = t; e < KTOP * CC; e += 256) { int k = e >> 6; pf[k][e & 63] *= invn[NBOX + k]; }
    __syncthreads();

    // --- sim + masked relu-margin sum ---
    float lsum = 0.f, cnt = 0.f;
    for (int p = t; p < NBOX * KTOP; p += 256) {
        int n = p / KTOP, k = p - n * KTOP;
        float dot = 0.f;
        for (int c = 0; c < CC; ++c) dot += df[n][c] * pf[k][c];
        if (s_static[n] && (topv[k] > -INFINITY)) {
            float r = dot - 0.5f;
            if (r > 0.f) lsum += r;
            cnt += 1.f;
        }
    }
    hv[t] = lsum;
    __shared__ float hc[256];
    hc[t] = cnt;
    __syncthreads();
    for (int s = 128; s > 0; s >>= 1) {
        if (t < s) { hv[t] += hv[t + s]; hc[t] += hc[t + s]; }
        __syncthreads();
    }
    if (t == 0) {
        float np = hc[0];
        bloss[b] = (np > 0.f) ? hv[0] / fmaxf(np, 1.0f) : 0.f;
    }
}

// ---------------- Kernel 4: final mean over batches ----------------
__global__ void k_final(const float* __restrict__ bloss, float* __restrict__ out, int B) {
    float s = 0.f;
    for (int b = 0; b < B; ++b) s += bloss[b];
    out[0] = s / (float)B;
}

extern "C" void kernel_launch(void* const* d_in, const int* in_sizes, int n_in,
                              void* d_out, int out_size, void* d_ws, size_t ws_size,
                              hipStream_t stream) {
    const float* loc   = (const float*)d_in[0];
    const float* det   = (const float*)d_in[1];
    const float* boxes = (const float*)d_in[2];
    float* out = (float*)d_out;

    int B = in_sizes[0] / (CC * HWHW);   // 4

    // workspace layout
    float* inten = (float*)d_ws;                            // B*HW floats
    float* cval  = inten + (size_t)B * HWHW;                // B*NBLK*KTOP floats
    int*   cidx  = (int*)(cval + (size_t)B * NBLK * KTOP);  // B*NBLK*KTOP ints
    float* bloss = (float*)(cidx + (size_t)B * NBLK * KTOP);// B floats

    dim3 blk(256);
    int g1 = (B * HWHW / 4) / 256;
    hipLaunchKernelGGL(k_intensity, dim3(g1), blk, 0, stream, loc, inten);
    hipLaunchKernelGGL(k_peaks, dim3(B * NBLK), blk, 0, stream, inten, cval, cidx);
    hipLaunchKernelGGL(k_loss, dim3(B), blk, 0, stream, loc, det, boxes, cval, cidx, bloss);
    hipLaunchKernelGGL(k_final, dim3(1), dim3(1), 0, stream, bloss, out, B);
}